// Round 12
// baseline (135.850 us; speedup 1.0000x reference)
//
#include <hip/hip_runtime.h>
#include <stdint.h>

#define RT    2336          // routes
#define RL    928           // LDS-resident routes per batch (32 + 7*128)
#define NSL2  8             // pass slices: ceil(RL*4/512); slice 7 covers 128
#define NRS2  11            // bf16 register residue slots: (RT-RL)/128 = 11
#define NTH   512
#define NBLK  1024          // one block per (b-pair, k), XCD swizzled
#define BATCH 1024
#define SH1   32.0f         // fixed softmax exponent shift, pass 2 (ratio cancels)
#define SH2   64.0f         // fixed softmax exponent shift, pass 3

__device__ __forceinline__ float blo(uint32_t v){ union {uint32_t u; float f;} x; x.u = v << 16;        return x.f; }
__device__ __forceinline__ float bhi(uint32_t v){ union {uint32_t u; float f;} x; x.u = v & 0xffff0000u; return x.f; }
__device__ __forceinline__ uint32_t f2b1(float f){          // fp32 -> bf16 (RNE)
  union {float f; uint32_t u;} x; x.f = f;
  return (x.u + 0x7fffu + ((x.u >> 16) & 1u)) >> 16;
}
__device__ __forceinline__ uint32_t f2b_pack(float a, float b){ return f2b1(a) | (f2b1(b) << 16); }
__device__ __forceinline__ uint2 pack4(float4 p){
  return make_uint2(f2b_pack(p.x, p.y), f2b_pack(p.z, p.w));
}

// Quad (4-lane) all-reduce sum via DPP quad_perm (VALU pipe, no LDS).
__device__ __forceinline__ float qsum4(float d){
  d += __int_as_float(__builtin_amdgcn_update_dpp(
         0, __float_as_int(d), 0xB1, 0xF, 0xF, true));
  d += __int_as_float(__builtin_amdgcn_update_dpp(
         0, __float_as_int(d), 0x4E, 0xF, 0xF, true));
  return d;
}

// Dual-batch block merge: batches A,B reduced in one barrier pair.
// tid<32 finishing stage: bt = tid>>4 selects batch; butterflies (masks <=8)
// stay inside each 16-lane group.
__device__ __forceinline__ void merge2(float4 aA, float lA, float4 aB, float lB,
                                       int tid, float (*red)[8][4][5],
                                       float (*vbuf)[16],
                                       bool last, float* outp){
  #pragma unroll
  for (int off = 32; off >= 4; off >>= 1){
    aA.x += __shfl_down(aA.x, off); aA.y += __shfl_down(aA.y, off);
    aA.z += __shfl_down(aA.z, off); aA.w += __shfl_down(aA.w, off);
    lA   += __shfl_down(lA,   off);
    aB.x += __shfl_down(aB.x, off); aB.y += __shfl_down(aB.y, off);
    aB.z += __shfl_down(aB.z, off); aB.w += __shfl_down(aB.w, off);
    lB   += __shfl_down(lB,   off);
  }
  const int lane = tid & 63, wid = tid >> 6;
  if (lane < 4){
    red[0][wid][lane][0] = lA;
    red[0][wid][lane][1] = aA.x; red[0][wid][lane][2] = aA.y;
    red[0][wid][lane][3] = aA.z; red[0][wid][lane][4] = aA.w;
    red[1][wid][lane][0] = lB;
    red[1][wid][lane][1] = aB.x; red[1][wid][lane][2] = aB.y;
    red[1][wid][lane][3] = aB.z; red[1][wid][lane][4] = aB.w;
  }
  __syncthreads();
  if (tid < 32){
    const int bt = tid >> 4, t = tid & 15, q = t >> 2, j = t & 3;
    float S = 0.f, partL = 0.f;
    #pragma unroll
    for (int w = 0; w < 8; ++w){
      S     += red[bt][w][q][1 + j];
      partL += red[bt][w][j][0];
    }
    partL += __shfl_xor(partL, 1);
    partL += __shfl_xor(partL, 2);
    float L   = partL * 0.25f;        // 4 qo-threads count each route once
    float inv = 1.f / L;
    float Sn  = S * inv;              // s = acc / L
    float nrm = Sn * Sn;              // squared norm over 16 outputs
    nrm += __shfl_xor(nrm, 1);
    nrm += __shfl_xor(nrm, 2);
    nrm += __shfl_xor(nrm, 4);
    nrm += __shfl_xor(nrm, 8);
    if (last){
      if (t == 0) outp[bt << 1] = nrm / (1.f + nrm);  // ||squash|| = n/(1+n)
    } else {
      float f = sqrtf(nrm) / (1.f + nrm);
      vbuf[bt][t] = Sn * f;
    }
  }
  __syncthreads();
}

// Batch-pair block (W loads shared, dual ILP chains). LDS 60,800 B: the
// session dataset shows 2 blocks/CU co-reside at <=63.5 KB but NOT at 77 KB
// (R10 occ 20% ~ 1 block) -> shrink RL 1184->928 to restore 2-block residency.
// launch_bounds arg=2 -> VGPR cap 128 (session model cap=512/(2*arg));
// body ~116 with 11+11 residue slots -> no spill expected (watch WRITE_SIZE).
__global__ void __launch_bounds__(NTH, 2)
caps_route(const float* __restrict__ U, const float* __restrict__ W,
           float* __restrict__ Out){
  __shared__ uint2 uj[2][RL * 4];     // [batch][route*4 + qo] : bf16x4
  __shared__ float red[2][8][4][5];
  __shared__ float vbuf[2][16];

  const int tid = threadIdx.x;
  const int qo  = tid & 3;            // my o-quad: o = 4*qo .. 4*qo+3

  // XCD swizzle: same XCD gets contiguous (pair,k) space; k=0/1 of one pair
  // adjacent -> u[b0],u[b1] L2 reuse; both W_k panels (1.2 MB) L2-resident.
  const int c    = blockIdx.x & 7;
  const int jj   = blockIdx.x >> 3;   // 0..127
  const int k    = jj & 1;
  const int pair = (c << 6) | (jj >> 1);   // 0..511, bijective
  const int bb   = pair << 1;         // b0 = bb, b1 = bb+1

  const float* Ub0 = U + (size_t)bb * (RT * 4);
  const float* Ub1 = Ub0 + (RT * 4);
  const float* Wk  = W + (size_t)k * ((size_t)RT * 64) + qo * 4;

  float4 accA, accB; float lA, lB;
  uint2  ura[NRS2], urb[NRS2];        // bf16-packed residue (same prec as LDS)
  float  vA0, vA1, vA2, vA3, vB0, vB1, vB2, vB3;

  // uji quads for both batches of route r; W row loaded once.
  auto build2 = [&](int route, float4& pa, float4& pb){
    float4 ua = *(const float4*)(Ub0 + (size_t)route * 4);
    float4 ub = *(const float4*)(Ub1 + (size_t)route * 4);
    const float* wr = Wk + (size_t)route * 64;
    float4 w0 = *(const float4*)(wr);
    float4 w1 = *(const float4*)(wr + 16);
    float4 w2 = *(const float4*)(wr + 32);
    float4 w3 = *(const float4*)(wr + 48);
    pa.x = ua.x * w0.x; pa.y = ua.x * w0.y; pa.z = ua.x * w0.z; pa.w = ua.x * w0.w;
    pa.x = fmaf(ua.y, w1.x, pa.x); pa.y = fmaf(ua.y, w1.y, pa.y);
    pa.z = fmaf(ua.y, w1.z, pa.z); pa.w = fmaf(ua.y, w1.w, pa.w);
    pa.x = fmaf(ua.z, w2.x, pa.x); pa.y = fmaf(ua.z, w2.y, pa.y);
    pa.z = fmaf(ua.z, w2.z, pa.z); pa.w = fmaf(ua.z, w2.w, pa.w);
    pa.x = fmaf(ua.w, w3.x, pa.x); pa.y = fmaf(ua.w, w3.y, pa.y);
    pa.z = fmaf(ua.w, w3.z, pa.z); pa.w = fmaf(ua.w, w3.w, pa.w);
    pb.x = ub.x * w0.x; pb.y = ub.x * w0.y; pb.z = ub.x * w0.z; pb.w = ub.x * w0.w;
    pb.x = fmaf(ub.y, w1.x, pb.x); pb.y = fmaf(ub.y, w1.y, pb.y);
    pb.z = fmaf(ub.y, w1.z, pb.z); pb.w = fmaf(ub.y, w1.w, pb.w);
    pb.x = fmaf(ub.z, w2.x, pb.x); pb.y = fmaf(ub.z, w2.y, pb.y);
    pb.z = fmaf(ub.z, w2.z, pb.z); pb.w = fmaf(ub.z, w2.w, pb.w);
    pb.x = fmaf(ub.w, w3.x, pb.x); pb.y = fmaf(ub.w, w3.y, pb.y);
    pb.z = fmaf(ub.w, w3.z, pb.z); pb.w = fmaf(ub.w, w3.w, pb.w);
  };

  // ---------------- Phase A: build u_ji both batches; fused pass 1 --------
  accA = make_float4(0.f,0.f,0.f,0.f); accB = make_float4(0.f,0.f,0.f,0.f);
  lA = 0.f; lB = 0.f;

  if (tid < 128){                     // pre-step: routes 0..31
    int route = tid >> 2;
    float4 pa, pb; build2(route, pa, pb);
    accA.x += pa.x; accA.y += pa.y; accA.z += pa.z; accA.w += pa.w; lA += 1.f;
    accB.x += pb.x; accB.y += pb.y; accB.z += pb.z; accB.w += pb.w; lB += 1.f;
    uj[0][route*4 + qo] = pack4(pa);
    uj[1][route*4 + qo] = pack4(pb);
  }
  #pragma unroll 3
  for (int s = 0; s < 7; ++s){        // LDS routes 32..927
    int route = 32 + s*128 + (tid >> 2);
    float4 pa, pb; build2(route, pa, pb);
    accA.x += pa.x; accA.y += pa.y; accA.z += pa.z; accA.w += pa.w; lA += 1.f;
    accB.x += pb.x; accB.y += pb.y; accB.z += pb.z; accB.w += pb.w; lB += 1.f;
    uj[0][route*4 + qo] = pack4(pa);
    uj[1][route*4 + qo] = pack4(pb);
  }
  #pragma unroll
  for (int slot = 0; slot < NRS2; ++slot){  // reg routes 928..2335, static
    int route = RL + slot*128 + (tid >> 2);
    float4 pa, pb; build2(route, pa, pb);
    accA.x += pa.x; accA.y += pa.y; accA.z += pa.z; accA.w += pa.w; lA += 1.f;
    accB.x += pb.x; accB.y += pb.y; accB.z += pb.z; accB.w += pb.w; lB += 1.f;
    ura[slot] = pack4(pa);
    urb[slot] = pack4(pb);
  }
  merge2(accA, lA, accB, lB, tid, red, vbuf, false, nullptr);   // v0 (A,B)
  vA0 = vbuf[0][4*qo]; vA1 = vbuf[0][4*qo+1]; vA2 = vbuf[0][4*qo+2]; vA3 = vbuf[0][4*qo+3];
  vB0 = vbuf[1][4*qo]; vB1 = vbuf[1][4*qo+1]; vB2 = vbuf[1][4*qo+2]; vB3 = vbuf[1][4*qo+3];

  // ---------------- Passes 2,3 (pass 3 uses vc = v0+v1; b starts at 0) ----
  for (int ps = 0; ps < 2; ++ps){
    const float SH = ps ? SH2 : SH1;
    accA = make_float4(0.f,0.f,0.f,0.f); accB = make_float4(0.f,0.f,0.f,0.f);
    lA = 0.f; lB = 0.f;
    #pragma unroll
    for (int s = 0; s < NSL2; ++s){   // LDS slices, idx = tid + 512*s
      int idx = tid + (s << 9);
      bool act = (idx < RL * 4);      // only s==7 partial (tid<128)
      float a0=0.f,a1=0.f,a2=0.f,a3=0.f, c0=0.f,c1=0.f,c2=0.f,c3=0.f;
      float dA = 0.f, dB = 0.f;
      if (act){
        uint2 qa = uj[0][idx], qb = uj[1][idx];
        a0 = blo(qa.x); a1 = bhi(qa.x); a2 = blo(qa.y); a3 = bhi(qa.y);
        c0 = blo(qb.x); c1 = bhi(qb.x); c2 = blo(qb.y); c3 = bhi(qb.y);
        dA = fmaf(a0, vA0, fmaf(a1, vA1, fmaf(a2, vA2, a3 * vA3)));
        dB = fmaf(c0, vB0, fmaf(c1, vB1, fmaf(c2, vB2, c3 * vB3)));
      }
      dA = qsum4(dA); dB = qsum4(dB);
      if (act){
        float eA = __expf(dA - SH), eB = __expf(dB - SH);
        lA += eA; lB += eB;
        accA.x = fmaf(eA, a0, accA.x); accA.y = fmaf(eA, a1, accA.y);
        accA.z = fmaf(eA, a2, accA.z); accA.w = fmaf(eA, a3, accA.w);
        accB.x = fmaf(eB, c0, accB.x); accB.y = fmaf(eB, c1, accB.y);
        accB.z = fmaf(eB, c2, accB.z); accB.w = fmaf(eB, c3, accB.w);
      }
    }
    #pragma unroll
    for (int slot = 0; slot < NRS2; ++slot){  // residue slices (all active)
      uint2 qa = ura[slot], qb = urb[slot];
      float a0 = blo(qa.x), a1 = bhi(qa.x), a2 = blo(qa.y), a3 = bhi(qa.y);
      float c0 = blo(qb.x), c1 = bhi(qb.x), c2 = blo(qb.y), c3 = bhi(qb.y);
      float dA = fmaf(a0, vA0, fmaf(a1, vA1, fmaf(a2, vA2, a3 * vA3)));
      float dB = fmaf(c0, vB0, fmaf(c1, vB1, fmaf(c2, vB2, c3 * vB3)));
      dA = qsum4(dA); dB = qsum4(dB);
      float eA = __expf(dA - SH), eB = __expf(dB - SH);
      lA += eA; lB += eB;
      accA.x = fmaf(eA, a0, accA.x); accA.y = fmaf(eA, a1, accA.y);
      accA.z = fmaf(eA, a2, accA.z); accA.w = fmaf(eA, a3, accA.w);
      accB.x = fmaf(eB, c0, accB.x); accB.y = fmaf(eB, c1, accB.y);
      accB.z = fmaf(eB, c2, accB.z); accB.w = fmaf(eB, c3, accB.w);
    }
    merge2(accA, lA, accB, lB, tid, red, vbuf, ps == 1,
           Out + (bb << 1) + k);      // last: Out[bb*2+k], Out[(bb+1)*2+k]
    if (ps == 0){                     // b2 = uji.(v0+v1): accumulate v
      vA0 += vbuf[0][4*qo]; vA1 += vbuf[0][4*qo+1];
      vA2 += vbuf[0][4*qo+2]; vA3 += vbuf[0][4*qo+3];
      vB0 += vbuf[1][4*qo]; vB1 += vbuf[1][4*qo+1];
      vB2 += vbuf[1][4*qo+2]; vB3 += vbuf[1][4*qo+3];
    }
  }
}

// In-place 2-way softmax over k: Out[b,0..1] fp32
__global__ void caps_softmax(float* __restrict__ Out){
  int b = blockIdx.x * blockDim.x + threadIdx.x;
  if (b < BATCH){
    float2* p = (float2*)Out;
    float2 c = p[b];
    float m  = fmaxf(c.x, c.y);
    float e0 = __expf(c.x - m), e1 = __expf(c.y - m);
    float inv = 1.f / (e0 + e1);
    p[b] = make_float2(e0 * inv, e1 * inv);
  }
}

extern "C" void kernel_launch(void* const* d_in, const int* in_sizes, int n_in,
                              void* d_out, int out_size, void* d_ws, size_t ws_size,
                              hipStream_t stream) {
  const float* U = (const float*)d_in[0];   // [1024, 2336, 4] fp32
  const float* W = (const float*)d_in[1];   // [2, 2336, 4, 16] fp32
  float* Out = (float*)d_out;               // [1024, 2] fp32
  caps_route<<<dim3(NBLK), dim3(NTH), 0, stream>>>(U, W, Out);
  caps_softmax<<<dim3(BATCH / 256), dim3(256), 0, stream>>>(Out);
}

// Round 13
// 133.498 us; speedup vs baseline: 1.0176x; 1.0176x over previous
//
#include <hip/hip_runtime.h>
#include <stdint.h>

#define RT    2336          // routes
#define RL    928           // LDS-resident routes per batch (32 + 7*128)
#define NSL2  8             // pass slices: ceil(RL*4/512); slice 7 covers 128
#define NRS2  11            // bf16 register residue slots: (RT-RL)/128 = 11
#define NTH   512
#define NBLK  1024          // one block per (b-pair, k), XCD swizzled
#define BATCH 1024
#define SH1   32.0f         // fixed softmax exponent shift, pass 2 (ratio cancels)
#define SH2   64.0f         // fixed softmax exponent shift, pass 3

typedef float v2f __attribute__((ext_vector_type(2)));

__device__ __forceinline__ float blo(uint32_t v){ union {uint32_t u; float f;} x; x.u = v << 16;        return x.f; }
__device__ __forceinline__ float bhi(uint32_t v){ union {uint32_t u; float f;} x; x.u = v & 0xffff0000u; return x.f; }

// 2x f32 -> packed bf16, ONE instruction (RNE on gfx950). Replaces the ~10-op
// manual f2b_pack; the pack was costing MORE VALU than the matmul FMAs.
__device__ __forceinline__ uint32_t cvtpk_bf16(float a, float b){
  uint32_t r;
  asm("v_cvt_pk_bf16_f32 %0, %1, %2" : "=v"(r) : "v"(a), "v"(b));
  return r;
}

// Packed 2x f32 VOP3P ops (gfx90a+): exact f32 math, half the issue count.
__device__ __forceinline__ v2f pk_fma(v2f a, v2f b, v2f c){
  v2f d; asm("v_pk_fma_f32 %0, %1, %2, %3" : "=v"(d) : "v"(a), "v"(b), "v"(c));
  return d;
}
__device__ __forceinline__ v2f pk_mul(v2f a, v2f b){
  v2f d; asm("v_pk_mul_f32 %0, %1, %2" : "=v"(d) : "v"(a), "v"(b));
  return d;
}
__device__ __forceinline__ v2f pk_add(v2f a, v2f b){
  v2f d; asm("v_pk_add_f32 %0, %1, %2" : "=v"(d) : "v"(a), "v"(b));
  return d;
}

// Quad (4-lane) all-reduce sum via DPP quad_perm (VALU pipe, no LDS).
__device__ __forceinline__ float qsum4(float d){
  d += __int_as_float(__builtin_amdgcn_update_dpp(
         0, __float_as_int(d), 0xB1, 0xF, 0xF, true));
  d += __int_as_float(__builtin_amdgcn_update_dpp(
         0, __float_as_int(d), 0x4E, 0xF, 0xF, true));
  return d;
}

// Dual-batch block merge: batches A,B reduced in one barrier pair.
__device__ __forceinline__ void merge2(float4 aA, float lA, float4 aB, float lB,
                                       int tid, float (*red)[8][4][5],
                                       float (*vbuf)[16],
                                       bool last, float* outp){
  #pragma unroll
  for (int off = 32; off >= 4; off >>= 1){
    aA.x += __shfl_down(aA.x, off); aA.y += __shfl_down(aA.y, off);
    aA.z += __shfl_down(aA.z, off); aA.w += __shfl_down(aA.w, off);
    lA   += __shfl_down(lA,   off);
    aB.x += __shfl_down(aB.x, off); aB.y += __shfl_down(aB.y, off);
    aB.z += __shfl_down(aB.z, off); aB.w += __shfl_down(aB.w, off);
    lB   += __shfl_down(lB,   off);
  }
  const int lane = tid & 63, wid = tid >> 6;
  if (lane < 4){
    red[0][wid][lane][0] = lA;
    red[0][wid][lane][1] = aA.x; red[0][wid][lane][2] = aA.y;
    red[0][wid][lane][3] = aA.z; red[0][wid][lane][4] = aA.w;
    red[1][wid][lane][0] = lB;
    red[1][wid][lane][1] = aB.x; red[1][wid][lane][2] = aB.y;
    red[1][wid][lane][3] = aB.z; red[1][wid][lane][4] = aB.w;
  }
  __syncthreads();
  if (tid < 32){
    const int bt = tid >> 4, t = tid & 15, q = t >> 2, j = t & 3;
    float S = 0.f, partL = 0.f;
    #pragma unroll
    for (int w = 0; w < 8; ++w){
      S     += red[bt][w][q][1 + j];
      partL += red[bt][w][j][0];
    }
    partL += __shfl_xor(partL, 1);
    partL += __shfl_xor(partL, 2);
    float L   = partL * 0.25f;        // 4 qo-threads count each route once
    float inv = 1.f / L;
    float Sn  = S * inv;              // s = acc / L
    float nrm = Sn * Sn;              // squared norm over 16 outputs
    nrm += __shfl_xor(nrm, 1);
    nrm += __shfl_xor(nrm, 2);
    nrm += __shfl_xor(nrm, 4);
    nrm += __shfl_xor(nrm, 8);
    if (last){
      if (t == 0) outp[bt << 1] = nrm / (1.f + nrm);  // ||squash|| = n/(1+n)
    } else {
      float f = sqrtf(nrm) / (1.f + nrm);
      vbuf[bt][t] = Sn * f;
    }
  }
  __syncthreads();
}

// Batch-pair block (W loads shared, dual ILP chains). Session facts: VGPR>64
// halves resident waves (R7/R10/R12 occ ~20% vs R3/R9 ~38-40%); LDS 51-77 KB
// doesn't move occupancy. So this round holds structure fixed and cuts VALU
// ISSUE count ~25% (cvt_pk pack, pk_fma build, uint4 LDS, const route-count).
__global__ void __launch_bounds__(NTH, 2)
caps_route(const float* __restrict__ U, const float* __restrict__ W,
           float* __restrict__ Out){
  __shared__ uint4 uj4[RL * 4];       // [route*4 + qo] : {A01,A23,B01,B23}
  __shared__ float red[2][8][4][5];
  __shared__ float vbuf[2][16];

  const int tid = threadIdx.x;
  const int qo  = tid & 3;            // my o-quad: o = 4*qo .. 4*qo+3

  // XCD swizzle (bijective): k=0/1 of one pair adjacent on same XCD.
  const int c    = blockIdx.x & 7;
  const int jj   = blockIdx.x >> 3;   // 0..127
  const int k    = jj & 1;
  const int pair = (c << 6) | (jj >> 1);   // 0..511
  const int bb   = pair << 1;         // b0 = bb, b1 = bb+1

  const float* Ub0 = U + (size_t)bb * (RT * 4);
  const float* Ub1 = Ub0 + (RT * 4);
  const float* Wk  = W + (size_t)k * ((size_t)RT * 64) + qo * 4;

  uint2  ura[NRS2], urb[NRS2];        // bf16-packed residue
  float  vA0, vA1, vA2, vA3, vB0, vB1, vB2, vB3;

  // uji quads for both batches of route r; W row loaded once; packed f32 FMA.
  auto build2 = [&](int route, v2f& pa01, v2f& pa23, v2f& pb01, v2f& pb23){
    float4 ua = *(const float4*)(Ub0 + (size_t)route * 4);
    float4 ub = *(const float4*)(Ub1 + (size_t)route * 4);
    const float* wr = Wk + (size_t)route * 64;
    float4 w0 = *(const float4*)(wr);
    float4 w1 = *(const float4*)(wr + 16);
    float4 w2 = *(const float4*)(wr + 32);
    float4 w3 = *(const float4*)(wr + 48);
    v2f w0l = {w0.x,w0.y}, w0h = {w0.z,w0.w};
    v2f w1l = {w1.x,w1.y}, w1h = {w1.z,w1.w};
    v2f w2l = {w2.x,w2.y}, w2h = {w2.z,w2.w};
    v2f w3l = {w3.x,w3.y}, w3h = {w3.z,w3.w};
    v2f sa0 = {ua.x,ua.x}, sa1 = {ua.y,ua.y}, sa2 = {ua.z,ua.z}, sa3 = {ua.w,ua.w};
    v2f sb0 = {ub.x,ub.x}, sb1 = {ub.y,ub.y}, sb2 = {ub.z,ub.z}, sb3 = {ub.w,ub.w};
    pa01 = pk_mul(sa0, w0l);          pa23 = pk_mul(sa0, w0h);
    pa01 = pk_fma(sa1, w1l, pa01);    pa23 = pk_fma(sa1, w1h, pa23);
    pa01 = pk_fma(sa2, w2l, pa01);    pa23 = pk_fma(sa2, w2h, pa23);
    pa01 = pk_fma(sa3, w3l, pa01);    pa23 = pk_fma(sa3, w3h, pa23);
    pb01 = pk_mul(sb0, w0l);          pb23 = pk_mul(sb0, w0h);
    pb01 = pk_fma(sb1, w1l, pb01);    pb23 = pk_fma(sb1, w1h, pb23);
    pb01 = pk_fma(sb2, w2l, pb01);    pb23 = pk_fma(sb2, w2h, pb23);
    pb01 = pk_fma(sb3, w3l, pb01);    pb23 = pk_fma(sb3, w3h, pb23);
  };

  // ---------------- Phase A: build u_ji both batches; fused pass 1 --------
  v2f accA01 = {0.f,0.f}, accA23 = {0.f,0.f};
  v2f accB01 = {0.f,0.f}, accB23 = {0.f,0.f};

  if (tid < 128){                     // pre-step: routes 0..31
    int route = tid >> 2;
    v2f pa01, pa23, pb01, pb23;
    build2(route, pa01, pa23, pb01, pb23);
    accA01 = pk_add(accA01, pa01); accA23 = pk_add(accA23, pa23);
    accB01 = pk_add(accB01, pb01); accB23 = pk_add(accB23, pb23);
    uj4[route*4 + qo] = make_uint4(
      cvtpk_bf16(pa01.x, pa01.y), cvtpk_bf16(pa23.x, pa23.y),
      cvtpk_bf16(pb01.x, pb01.y), cvtpk_bf16(pb23.x, pb23.y));
  }
  #pragma unroll 3
  for (int s = 0; s < 7; ++s){        // LDS routes 32..927
    int route = 32 + s*128 + (tid >> 2);
    v2f pa01, pa23, pb01, pb23;
    build2(route, pa01, pa23, pb01, pb23);
    accA01 = pk_add(accA01, pa01); accA23 = pk_add(accA23, pa23);
    accB01 = pk_add(accB01, pb01); accB23 = pk_add(accB23, pb23);
    uj4[route*4 + qo] = make_uint4(
      cvtpk_bf16(pa01.x, pa01.y), cvtpk_bf16(pa23.x, pa23.y),
      cvtpk_bf16(pb01.x, pb01.y), cvtpk_bf16(pb23.x, pb23.y));
  }
  #pragma unroll
  for (int slot = 0; slot < NRS2; ++slot){  // reg routes 928..2335, static
    int route = RL + slot*128 + (tid >> 2);
    v2f pa01, pa23, pb01, pb23;
    build2(route, pa01, pa23, pb01, pb23);
    accA01 = pk_add(accA01, pa01); accA23 = pk_add(accA23, pa23);
    accB01 = pk_add(accB01, pb01); accB23 = pk_add(accB23, pb23);
    ura[slot] = make_uint2(cvtpk_bf16(pa01.x, pa01.y), cvtpk_bf16(pa23.x, pa23.y));
    urb[slot] = make_uint2(cvtpk_bf16(pb01.x, pb01.y), cvtpk_bf16(pb23.x, pb23.y));
  }
  // route counts are compile-time (pre-step threads handle one extra route)
  float lA = (tid < 128) ? 19.f : 18.f, lB = lA;
  merge2(make_float4(accA01.x, accA01.y, accA23.x, accA23.y), lA,
         make_float4(accB01.x, accB01.y, accB23.x, accB23.y), lB,
         tid, red, vbuf, false, nullptr);                     // v0 (A,B)
  vA0 = vbuf[0][4*qo]; vA1 = vbuf[0][4*qo+1]; vA2 = vbuf[0][4*qo+2]; vA3 = vbuf[0][4*qo+3];
  vB0 = vbuf[1][4*qo]; vB1 = vbuf[1][4*qo+1]; vB2 = vbuf[1][4*qo+2]; vB3 = vbuf[1][4*qo+3];

  // ---------------- Passes 2,3 (pass 3 uses vc = v0+v1; b starts at 0) ----
  for (int ps = 0; ps < 2; ++ps){
    const float SH = ps ? SH2 : SH1;
    float4 accA = make_float4(0.f,0.f,0.f,0.f), accB = make_float4(0.f,0.f,0.f,0.f);
    float lpA = 0.f, lpB = 0.f;
    #pragma unroll
    for (int s = 0; s < NSL2; ++s){   // LDS slices, idx = tid + 512*s
      int idx = tid + (s << 9);
      bool act = (idx < RL * 4);      // only s==7 partial (tid<128)
      float a0=0.f,a1=0.f,a2=0.f,a3=0.f, c0=0.f,c1=0.f,c2=0.f,c3=0.f;
      float dA = 0.f, dB = 0.f;
      if (act){
        uint4 q4 = uj4[idx];          // one ds_read_b128: both batches
        a0 = blo(q4.x); a1 = bhi(q4.x); a2 = blo(q4.y); a3 = bhi(q4.y);
        c0 = blo(q4.z); c1 = bhi(q4.z); c2 = blo(q4.w); c3 = bhi(q4.w);
        dA = fmaf(a0, vA0, fmaf(a1, vA1, fmaf(a2, vA2, a3 * vA3)));
        dB = fmaf(c0, vB0, fmaf(c1, vB1, fmaf(c2, vB2, c3 * vB3)));
      }
      dA = qsum4(dA); dB = qsum4(dB);
      if (act){
        float eA = __expf(dA - SH), eB = __expf(dB - SH);
        lpA += eA; lpB += eB;
        accA.x = fmaf(eA, a0, accA.x); accA.y = fmaf(eA, a1, accA.y);
        accA.z = fmaf(eA, a2, accA.z); accA.w = fmaf(eA, a3, accA.w);
        accB.x = fmaf(eB, c0, accB.x); accB.y = fmaf(eB, c1, accB.y);
        accB.z = fmaf(eB, c2, accB.z); accB.w = fmaf(eB, c3, accB.w);
      }
    }
    #pragma unroll
    for (int slot = 0; slot < NRS2; ++slot){  // residue slices (all active)
      uint2 qa = ura[slot], qb = urb[slot];
      float a0 = blo(qa.x), a1 = bhi(qa.x), a2 = blo(qa.y), a3 = bhi(qa.y);
      float c0 = blo(qb.x), c1 = bhi(qb.x), c2 = blo(qb.y), c3 = bhi(qb.y);
      float dA = fmaf(a0, vA0, fmaf(a1, vA1, fmaf(a2, vA2, a3 * vA3)));
      float dB = fmaf(c0, vB0, fmaf(c1, vB1, fmaf(c2, vB2, c3 * vB3)));
      dA = qsum4(dA); dB = qsum4(dB);
      float eA = __expf(dA - SH), eB = __expf(dB - SH);
      lpA += eA; lpB += eB;
      accA.x = fmaf(eA, a0, accA.x); accA.y = fmaf(eA, a1, accA.y);
      accA.z = fmaf(eA, a2, accA.z); accA.w = fmaf(eA, a3, accA.w);
      accB.x = fmaf(eB, c0, accB.x); accB.y = fmaf(eB, c1, accB.y);
      accB.z = fmaf(eB, c2, accB.z); accB.w = fmaf(eB, c3, accB.w);
    }
    merge2(accA, lpA, accB, lpB, tid, red, vbuf, ps == 1,
           Out + (bb << 1) + k);      // last: Out[bb*2+k], Out[(bb+1)*2+k]
    if (ps == 0){                     // b2 = uji.(v0+v1): accumulate v
      vA0 += vbuf[0][4*qo]; vA1 += vbuf[0][4*qo+1];
      vA2 += vbuf[0][4*qo+2]; vA3 += vbuf[0][4*qo+3];
      vB0 += vbuf[1][4*qo]; vB1 += vbuf[1][4*qo+1];
      vB2 += vbuf[1][4*qo+2]; vB3 += vbuf[1][4*qo+3];
    }
  }
}

// In-place 2-way softmax over k: Out[b,0..1] fp32
__global__ void caps_softmax(float* __restrict__ Out){
  int b = blockIdx.x * blockDim.x + threadIdx.x;
  if (b < BATCH){
    float2* p = (float2*)Out;
    float2 c = p[b];
    float m  = fmaxf(c.x, c.y);
    float e0 = __expf(c.x - m), e1 = __expf(c.y - m);
    float inv = 1.f / (e0 + e1);
    p[b] = make_float2(e0 * inv, e1 * inv);
  }
}

extern "C" void kernel_launch(void* const* d_in, const int* in_sizes, int n_in,
                              void* d_out, int out_size, void* d_ws, size_t ws_size,
                              hipStream_t stream) {
  const float* U = (const float*)d_in[0];   // [1024, 2336, 4] fp32
  const float* W = (const float*)d_in[1];   // [2, 2336, 4, 16] fp32
  float* Out = (float*)d_out;               // [1024, 2] fp32
  caps_route<<<dim3(NBLK), dim3(NTH), 0, stream>>>(U, W, Out);
  caps_softmax<<<dim3(BATCH / 256), dim3(256), 0, stream>>>(Out);
}